// Round 1
// 422.677 us; speedup vs baseline: 1.2140x; 1.2140x over previous
//
#include <hip/hip_runtime.h>

typedef _Float16 f16;
typedef __attribute__((ext_vector_type(8))) _Float16 f16x8;
typedef __attribute__((ext_vector_type(4))) _Float16 f16x4;
typedef __attribute__((ext_vector_type(4))) float f32x4;

constexpr int B_ = 8, LQ = 1024, LK = 2048, NH = 16, HID = 1024;

// async global->LDS, 16B per lane; LDS dest must be wave-uniform base + lane*16
__device__ __forceinline__ void gll16(const void* g, void* l) {
  __builtin_amdgcn_global_load_lds((const __attribute__((address_space(1))) void*)g,
                                   (__attribute__((address_space(3))) void*)l, 16, 0, 0);
}

// ---------- fp32 -> fp16 cast (vectorized) ----------
__global__ __launch_bounds__(256) void cvt_f32_f16(const float* __restrict__ src,
                                                   f16* __restrict__ dst, int n4) {
  int t = blockIdx.x * 256 + threadIdx.x;
  if (t >= n4) return;
  float4 v = ((const float4*)src)[t];
  f16x4 o = {(f16)v.x, (f16)v.y, (f16)v.z, (f16)v.w};
  ((f16x4*)dst)[t] = o;
}

// ---------- fused NT GEMM: C[M,N] = A[M,K] * B[N,K]^T ----------
// MODE 0: Q proj -> RoPE -> Qb [bh][lq][64]           (out0=Qb, linear rows)
// MODE 1: KV proj -> wn=0: RoPE K -> Kb [bh][lk][64]  (row-XOR-swizzled for attn LDS)
//                    wn=1: V^T -> Vt [bh][kc][dv][64] (row-XOR-swizzled for attn LDS)
// MODE 2: plain fp32 output (out0)
template <int MODE>
__global__ __launch_bounds__(256) void gemm_fused(const f16* __restrict__ A,
                                                  const f16* __restrict__ Bm,
                                                  void* __restrict__ out0,
                                                  void* __restrict__ out1,
                                                  int M, int N, int K) {
  const int n0 = blockIdx.x * 128, m0 = blockIdx.y * 128;
  const int tid = threadIdx.x, lane = tid & 63, w = tid >> 6;
  const int wm = w >> 1, wn = w & 1;
  const int quad = lane >> 4, l16 = lane & 15;
  __shared__ __align__(16) f16 As[128 * 64];
  __shared__ __align__(16) f16 Bs[128 * 64];
  f32x4 acc[4][4] = {};
  const int sr = tid >> 3, sc = (tid & 7) * 8;
  const f16* ga = A + (size_t)(m0 + sr) * K + sc;
  const f16* gb = Bm + (size_t)(n0 + sr) * K + sc;
  for (int k0 = 0; k0 < K; k0 += 64) {
    __syncthreads();
#pragma unroll
    for (int p = 0; p < 4; ++p) {
      gll16(ga + (size_t)p * 32 * K + k0, &As[(sr + p * 32) * 64 + sc]);
      gll16(gb + (size_t)p * 32 * K + k0, &Bs[(sr + p * 32) * 64 + sc]);
    }
    __syncthreads();
#pragma unroll
    for (int ks = 0; ks < 2; ++ks) {
      f16x8 af[4], bfr[4];
#pragma unroll
      for (int i = 0; i < 4; ++i) {
        af[i] = *(const f16x8*)&As[(wm * 64 + i * 16 + l16) * 64 + ks * 32 + quad * 8];
        bfr[i] = *(const f16x8*)&Bs[(wn * 64 + i * 16 + l16) * 64 + ks * 32 + quad * 8];
      }
#pragma unroll
      for (int i = 0; i < 4; ++i)
#pragma unroll
        for (int j = 0; j < 4; ++j)
          acc[i][j] = __builtin_amdgcn_mfma_f32_16x16x32_f16(af[i], bfr[j], acc[i][j], 0, 0, 0);
    }
  }
  if (MODE == 2) {
#pragma unroll
    for (int i = 0; i < 4; ++i)
#pragma unroll
      for (int j = 0; j < 4; ++j) {
        int row = m0 + wm * 64 + i * 16 + quad * 4;
        int col = n0 + wn * 64 + j * 16 + l16;
#pragma unroll
        for (int r = 0; r < 4; ++r)
          ((float*)out0)[(size_t)(row + r) * N + col] = acc[i][j][r];
      }
    return;
  }
  constexpr int LSH = (MODE == 0) ? 10 : 11;
  constexpr int LMSK = (MODE == 0) ? 1023 : 2047;
  const int Ltok = LMSK + 1;
  if (MODE == 0 || wn == 0) {
    // RoPE path. col c: head h = c / headspan, d = (c per-head K-dim index)
#pragma unroll
    for (int j = 0; j < 4; ++j) {
      int c = n0 + wn * 64 + j * 16 + l16;
      int h = (MODE == 0) ? (c >> 6) : (n0 >> 7);
      int d = (MODE == 0) ? (c & 63) : (j * 16 + l16);
      float inv_t = exp2f((float)(d >> 1) * -0.41524101186091903f);
#pragma unroll
      for (int i = 0; i < 4; ++i) {
        f32x4 v = acc[i][j];
        f32x4 pv;
#pragma unroll
        for (int r = 0; r < 4; ++r) pv[r] = __shfl_xor(v[r], 1, 64);
        int row0 = m0 + wm * 64 + i * 16 + quad * 4;
#pragma unroll
        for (int r = 0; r < 4; ++r) {
          int row = row0 + r;
          int pos = row & LMSK, b = row >> LSH;
          float ang = (float)pos * inv_t;
          float sn, cs;
          __sincosf(ang, &sn, &cs);
          float o = (d & 1) ? (v[r] * cs + pv[r] * sn) : (v[r] * cs - pv[r] * sn);
          // K rows get the attn-LDS XOR swizzle pre-applied (16B chunks within 128B row)
          int dsw = (MODE == 1) ? (d ^ ((pos & 7) << 3)) : d;
          ((f16*)out0)[(((size_t)b * NH + h) * Ltok + pos) * 64 + dsw] = (f16)o;
        }
      }
    }
  } else {
    // V path (MODE 1, wn==1): V^T tiled: Vt[((bh*32 + kc)*64 + dv)*64 + klo], row=dv swizzled
    const int h = n0 >> 7;
#pragma unroll
    for (int j = 0; j < 4; ++j) {
      int dv = j * 16 + l16;
#pragma unroll
      for (int i = 0; i < 4; ++i) {
        int row0 = m0 + wm * 64 + i * 16 + quad * 4;
        int pos0 = row0 & 2047, b = row0 >> 11;
        int kc = pos0 >> 6, klo = pos0 & 63;
        f32x4 v = acc[i][j];
        f16x4 pk = {(f16)v[0], (f16)v[1], (f16)v[2], (f16)v[3]};
        int klosw = klo ^ ((dv & 7) << 3);  // pre-swizzle for attn LDS read
        *(f16x4*)&((f16*)out1)[((((size_t)b * NH + h) * 32 + kc) * 64 + dv) * 64 + klosw] = pk;
      }
    }
  }
}

// ---------- flash attention ----------
// grid (B*NH, LQ/128), 256 threads (4 waves). Each wave: 32 q-rows x full D=64.
// Swapped QK^T: sacc = mfma(A=K, B=Q) -> lane holds P[q=l16][k=16nt+quad*4+r],
// which IS the B-fragment of mfma_f32_16x16x16f16 -> PV runs straight from registers
// (no P LDS round-trip). O^T = mfma(A=V^T frag, B=P^T); row-sum via ones-A mfma.
// Kb/Vt arrive pre-XOR-swizzled (byte^((row&7)<<4)) so global_load_lds stays linear.
__global__ __launch_bounds__(256, 4) void attn(const f16* __restrict__ Qb,
                                               const f16* __restrict__ Kb,
                                               const f16* __restrict__ Vt,
                                               f16* __restrict__ attnb) {
  const int bh = blockIdx.x, b = bh >> 4, h = bh & 15;
  const int q0 = blockIdx.y * 128;
  const int tid = threadIdx.x, lane = tid & 63, w = tid >> 6;
  const int quad = lane >> 4, l16 = lane & 15;
  const int sw = (l16 & 7) << 3;
  __shared__ __align__(16) f16 Ks[64 * 64];
  __shared__ __align__(16) f16 Vts[64 * 64];
  // Q rows for this wave: q0 + 32*w + qs*16 + l16 (Qb is linear, read to regs)
  const f16* qptr = Qb + ((size_t)bh * LQ + q0 + 32 * w + l16) * 64;
  f16x8 qf[2][2];
#pragma unroll
  for (int qs = 0; qs < 2; ++qs) {
    qf[qs][0] = *(const f16x8*)&qptr[qs * 16 * 64 + quad * 8];
    qf[qs][1] = *(const f16x8*)&qptr[qs * 16 * 64 + 32 + quad * 8];
  }
  const f16x4 ones4 = {(f16)1.f, (f16)1.f, (f16)1.f, (f16)1.f};
  f32x4 o[2][4] = {};
  f32x4 lacc[2] = {};
  float m_run[2] = {-1e30f, -1e30f};
  const f16* kbase = Kb + (size_t)bh * LK * 64;
  const f16* vtb = Vt + (size_t)bh * 32 * 4096;
  const int sr = tid >> 3, sc = (tid & 7) * 8;
  for (int c = 0; c < LK / 64; ++c) {
    __syncthreads();
    // stage K,V chunk via DMA (dest linear: per wave = base + lane*16)
    gll16(kbase + (size_t)(c * 64 + sr) * 64 + sc, &Ks[sr * 64 + sc]);
    gll16(kbase + (size_t)(c * 64 + sr + 32) * 64 + sc, &Ks[(sr + 32) * 64 + sc]);
    gll16(vtb + (size_t)(c * 64 + sr) * 64 + sc, &Vts[sr * 64 + sc]);
    gll16(vtb + (size_t)(c * 64 + sr + 32) * 64 + sc, &Vts[(sr + 32) * 64 + sc]);
    __syncthreads();
    // S^T = K Q^T : lane gets S[q=l16][k=nt*16+quad*4+r]
    f32x4 sacc[2][4] = {};
#pragma unroll
    for (int nt = 0; nt < 4; ++nt) {
      const f16* krow = &Ks[(nt * 16 + l16) * 64];
      f16x8 kf0 = *(const f16x8*)&krow[(quad * 8) ^ sw];
      f16x8 kf1 = *(const f16x8*)&krow[(32 + quad * 8) ^ sw];
#pragma unroll
      for (int qs = 0; qs < 2; ++qs) {
        sacc[qs][nt] = __builtin_amdgcn_mfma_f32_16x16x32_f16(kf0, qf[qs][0], sacc[qs][nt], 0, 0, 0);
        sacc[qs][nt] = __builtin_amdgcn_mfma_f32_16x16x32_f16(kf1, qf[qs][1], sacc[qs][nt], 0, 0, 0);
      }
    }
    // in-register online softmax (per-lane row max; cross-quad reduce only)
    f16x4 pb[2][4];
#pragma unroll
    for (int qs = 0; qs < 2; ++qs) {
      float mx = sacc[qs][0][0];
#pragma unroll
      for (int nt = 0; nt < 4; ++nt)
#pragma unroll
        for (int r = 0; r < 4; ++r) mx = fmaxf(mx, sacc[qs][nt][r]);
      mx = fmaxf(mx, __shfl_xor(mx, 16, 64));
      mx = fmaxf(mx, __shfl_xor(mx, 32, 64));
      // defer-max: only rescale when max grew by > 8 (P bounded by e^8, f16-safe)
      if (!__all(mx <= m_run[qs] + 8.0f)) {
        float mn = fmaxf(m_run[qs], mx);
        float al = __expf(m_run[qs] - mn);
        m_run[qs] = mn;
#pragma unroll
        for (int r = 0; r < 4; ++r) lacc[qs][r] *= al;
#pragma unroll
        for (int dt = 0; dt < 4; ++dt)
#pragma unroll
          for (int r = 0; r < 4; ++r) o[qs][dt][r] *= al;
      }
      float m = m_run[qs];
#pragma unroll
      for (int nt = 0; nt < 4; ++nt) {
        f16x4 p;
#pragma unroll
        for (int r = 0; r < 4; ++r) p[r] = (f16)__expf(sacc[qs][nt][r] - m);
        pb[qs][nt] = p;
        // row-sum of P on the MFMA pipe: D[i][q] += sum_k 1 * P^T[k][q]
        lacc[qs] = __builtin_amdgcn_mfma_f32_16x16x16f16(ones4, p, lacc[qs], 0, 0, 0);
      }
    }
    // O^T += V^T P^T  (A = V^T fragment from LDS, B = P^T straight from registers)
#pragma unroll
    for (int dt = 0; dt < 4; ++dt)
#pragma unroll
      for (int nt = 0; nt < 4; ++nt) {
        f16x4 vf = *(const f16x4*)&Vts[(dt * 16 + l16) * 64 + ((nt * 16 + quad * 4) ^ sw)];
#pragma unroll
        for (int qs = 0; qs < 2; ++qs)
          o[qs][dt] = __builtin_amdgcn_mfma_f32_16x16x16f16(vf, pb[qs][nt], o[qs][dt], 0, 0, 0);
      }
  }
  // epilogue: o holds O^T (lane: dv = dt*16+quad*4+r, q = l16) -> f16x4 stores
#pragma unroll
  for (int qs = 0; qs < 2; ++qs) {
    float inv = 1.0f / lacc[qs][0];
    int q = q0 + 32 * w + qs * 16 + l16;
#pragma unroll
    for (int dt = 0; dt < 4; ++dt) {
      f16x4 ov;
#pragma unroll
      for (int r = 0; r < 4; ++r) ov[r] = (f16)(o[qs][dt][r] * inv);
      *(f16x4*)&attnb[((size_t)b * LQ + q) * HID + h * 64 + dt * 16 + quad * 4] = ov;
    }
  }
}

extern "C" void kernel_launch(void* const* d_in, const int* in_sizes, int n_in,
                              void* d_out, int out_size, void* d_ws, size_t ws_size,
                              hipStream_t stream) {
  const float* x = (const float*)d_in[0];
  const float* y = (const float*)d_in[1];
  const float* Wq = (const float*)d_in[2];
  const float* Wkv = (const float*)d_in[3];
  const float* Wo = (const float*)d_in[4];
  float* out = (float*)d_out;

  char* p = (char*)d_ws;
  f16* xb = (f16*)p;    p += (size_t)B_ * LQ * HID * 2;      // 16 MB
  f16* yb = (f16*)p;    p += (size_t)B_ * LK * HID * 2;      // 32 MB
  f16* Wqb = (f16*)p;   p += (size_t)HID * HID * 2;          // 2 MB
  f16* Wkvb = (f16*)p;  p += (size_t)2 * HID * HID * 2;      // 4 MB
  f16* Wob = (f16*)p;   p += (size_t)HID * HID * 2;          // 2 MB
  f16* Qb = (f16*)p;    p += (size_t)B_ * LQ * HID * 2;      // 16 MB
  f16* Kb = (f16*)p;    p += (size_t)B_ * LK * HID * 2;      // 32 MB
  f16* Vt = (f16*)p;    p += (size_t)B_ * LK * HID * 2;      // 32 MB
  f16* attnb = xb;  // xb dead after GEMM1

  auto cvt = [&](const float* s, f16* d, size_t n) {
    cvt_f32_f16<<<dim3((unsigned)((n / 4 + 255) / 256)), 256, 0, stream>>>(s, d, (int)(n / 4));
  };
  cvt(x, xb, (size_t)B_ * LQ * HID);
  cvt(y, yb, (size_t)B_ * LK * HID);
  cvt(Wq, Wqb, (size_t)HID * HID);
  cvt(Wkv, Wkvb, (size_t)2 * HID * HID);
  cvt(Wo, Wob, (size_t)HID * HID);

  // Q = RoPE(x @ Wq^T) -> Qb [bh][lq][64]
  gemm_fused<0><<<dim3(HID / 128, B_ * LQ / 128), 256, 0, stream>>>(
      xb, Wqb, Qb, nullptr, B_ * LQ, HID, HID);
  // KV = y @ Wkv^T -> Kb (RoPE, swizzled) + Vt (transposed, chunk-tiled, swizzled)
  gemm_fused<1><<<dim3(2 * HID / 128, B_ * LK / 128), 256, 0, stream>>>(
      yb, Wkvb, Kb, Vt, B_ * LK, 2 * HID, HID);

  // attention -> attnb [B*LQ, 1024] fp16; grid bh-major so a head's K/V pins to one XCD L2
  attn<<<dim3(B_ * NH, LQ / 128), 256, 0, stream>>>(Qb, Kb, Vt, attnb);

  // out = attn @ Wo^T -> fp32
  gemm_fused<2><<<dim3(HID / 128, B_ * LQ / 128), 256, 0, stream>>>(
      attnb, Wob, out, nullptr, B_ * LQ, HID, HID);
}

// Round 3
// 414.123 us; speedup vs baseline: 1.2390x; 1.0207x over previous
//
#include <hip/hip_runtime.h>

typedef _Float16 f16;
typedef __attribute__((ext_vector_type(8))) _Float16 f16x8;
typedef __attribute__((ext_vector_type(4))) _Float16 f16x4;
typedef __attribute__((ext_vector_type(4))) float f32x4;

constexpr int B_ = 8, LQ = 1024, LK = 2048, NH = 16, HID = 1024;

// async global->LDS, 16B per lane; LDS dest must be wave-uniform base + lane*16
__device__ __forceinline__ void gll16(const void* g, void* l) {
  __builtin_amdgcn_global_load_lds((const __attribute__((address_space(1))) void*)g,
                                   (__attribute__((address_space(3))) void*)l, 16, 0, 0);
}

// ---------- fp32 -> fp16 cast (vectorized) ----------
__global__ __launch_bounds__(256) void cvt_f32_f16(const float* __restrict__ src,
                                                   f16* __restrict__ dst, int n4) {
  int t = blockIdx.x * 256 + threadIdx.x;
  if (t >= n4) return;
  float4 v = ((const float4*)src)[t];
  f16x4 o = {(f16)v.x, (f16)v.y, (f16)v.z, (f16)v.w};
  ((f16x4*)dst)[t] = o;
}

// ---------- fused NT GEMM: C[M,N] = A[M,K] * B[N,K]^T ----------
// Proven 2-phase pipeline (T3 minimal recipe): STAGE(t+1) issued first, compute
// tile t while loads fly, then ONE vmcnt(0)+s_barrier per tile, sched_barrier(0)
// pinning compiler motion across the raw barrier. Linear LDS (no swizzle this rev).
// T5 setprio around MFMA cluster, T1 bijective XCD-chunked block remap.
// MODE 0: Q proj -> RoPE -> Qb [bh][lq][64]           (out0=Qb, linear rows)
// MODE 1: KV proj -> wn=0: RoPE K -> Kb [bh][lk][64]  (row-XOR-swizzled for attn LDS)
//                    wn=1: V^T -> Vt [bh][kc][dv][64] (row-XOR-swizzled for attn LDS)
// MODE 2: plain fp32 output (out0)
template <int MODE>
__global__ __launch_bounds__(256) void gemm_fused(const f16* __restrict__ A,
                                                  const f16* __restrict__ Bm,
                                                  void* __restrict__ out0,
                                                  void* __restrict__ out1,
                                                  int M, int N, int K) {
  // T1: chunked XCD remap (requires nwg % 8 == 0 -- true for all launches here)
  const int gx = gridDim.x;
  const int nwg = gx * gridDim.y;
  const int cpx = nwg >> 3;
  const int fid = blockIdx.y * gx + blockIdx.x;
  const int lid = (fid & 7) * cpx + (fid >> 3);
  const int n0 = (lid % gx) * 128, m0 = (lid / gx) * 128;
  const int tid = threadIdx.x, lane = tid & 63, w = tid >> 6;
  const int wm = w >> 1, wn = w & 1;
  const int quad = lane >> 4, l16 = lane & 15;
  __shared__ __align__(16) f16 As[2][128 * 64];
  __shared__ __align__(16) f16 Bs[2][128 * 64];
  f32x4 acc[4][4] = {};
  const int sr = tid >> 3, sc = (tid & 7) * 8;
  const f16* ga = A + (size_t)(m0 + sr) * K + sc;
  const f16* gb = Bm + (size_t)(n0 + sr) * K + sc;
  const int NT = K >> 6;

  auto STAGE = [&](int t) {
    f16* as = As[t & 1];
    f16* bs = Bs[t & 1];
    const int k0 = t << 6;
#pragma unroll
    for (int p = 0; p < 4; ++p) {
      gll16(ga + (size_t)p * 32 * K + k0, &as[(sr + p * 32) * 64 + sc]);
      gll16(gb + (size_t)p * 32 * K + k0, &bs[(sr + p * 32) * 64 + sc]);
    }
  };

  // prologue: stage tile 0, full drain, join
  STAGE(0);
  asm volatile("s_waitcnt vmcnt(0)" ::: "memory");
  __builtin_amdgcn_s_barrier();
  __builtin_amdgcn_sched_barrier(0);

  for (int t = 0; t < NT; ++t) {
    if (t + 1 < NT) STAGE(t + 1);  // issue next tile; latency hides under MFMAs below
    const f16* as = As[t & 1];
    const f16* bs = Bs[t & 1];
#pragma unroll
    for (int ks = 0; ks < 2; ++ks) {
      f16x8 af[4], bfr[4];
#pragma unroll
      for (int i = 0; i < 4; ++i) {
        af[i] = *(const f16x8*)&as[(wm * 64 + i * 16 + l16) * 64 + ks * 32 + quad * 8];
        bfr[i] = *(const f16x8*)&bs[(wn * 64 + i * 16 + l16) * 64 + ks * 32 + quad * 8];
      }
      __builtin_amdgcn_s_setprio(1);
#pragma unroll
      for (int i = 0; i < 4; ++i)
#pragma unroll
        for (int j = 0; j < 4; ++j)
          acc[i][j] = __builtin_amdgcn_mfma_f32_16x16x32_f16(af[i], bfr[j], acc[i][j], 0, 0, 0);
      __builtin_amdgcn_s_setprio(0);
    }
    // next tile fully landed (own loads) + all waves done reading current buf
    asm volatile("s_waitcnt vmcnt(0)" ::: "memory");
    __builtin_amdgcn_s_barrier();
    __builtin_amdgcn_sched_barrier(0);
  }
  if (MODE == 2) {
#pragma unroll
    for (int i = 0; i < 4; ++i)
#pragma unroll
      for (int j = 0; j < 4; ++j) {
        int row = m0 + wm * 64 + i * 16 + quad * 4;
        int col = n0 + wn * 64 + j * 16 + l16;
#pragma unroll
        for (int r = 0; r < 4; ++r)
          ((float*)out0)[(size_t)(row + r) * N + col] = acc[i][j][r];
      }
    return;
  }
  constexpr int LSH = (MODE == 0) ? 10 : 11;
  constexpr int LMSK = (MODE == 0) ? 1023 : 2047;
  const int Ltok = LMSK + 1;
  if (MODE == 0 || wn == 0) {
    // RoPE path. col c: head h = c / headspan, d = (c per-head K-dim index)
#pragma unroll
    for (int j = 0; j < 4; ++j) {
      int c = n0 + wn * 64 + j * 16 + l16;
      int h = (MODE == 0) ? (c >> 6) : (n0 >> 7);
      int d = (MODE == 0) ? (c & 63) : (j * 16 + l16);
      float inv_t = exp2f((float)(d >> 1) * -0.41524101186091903f);
#pragma unroll
      for (int i = 0; i < 4; ++i) {
        f32x4 v = acc[i][j];
        f32x4 pv;
#pragma unroll
        for (int r = 0; r < 4; ++r) pv[r] = __shfl_xor(v[r], 1, 64);
        int row0 = m0 + wm * 64 + i * 16 + quad * 4;
#pragma unroll
        for (int r = 0; r < 4; ++r) {
          int row = row0 + r;
          int pos = row & LMSK, b = row >> LSH;
          float ang = (float)pos * inv_t;
          float sn, cs;
          __sincosf(ang, &sn, &cs);
          float o = (d & 1) ? (v[r] * cs + pv[r] * sn) : (v[r] * cs - pv[r] * sn);
          // K rows get the attn-LDS XOR swizzle pre-applied (16B chunks within 128B row)
          int dsw = (MODE == 1) ? (d ^ ((pos & 7) << 3)) : d;
          ((f16*)out0)[(((size_t)b * NH + h) * Ltok + pos) * 64 + dsw] = (f16)o;
        }
      }
    }
  } else {
    // V path (MODE 1, wn==1): V^T tiled: Vt[((bh*32 + kc)*64 + dv)*64 + klo], row=dv swizzled
    const int h = n0 >> 7;
#pragma unroll
    for (int j = 0; j < 4; ++j) {
      int dv = j * 16 + l16;
#pragma unroll
      for (int i = 0; i < 4; ++i) {
        int row0 = m0 + wm * 64 + i * 16 + quad * 4;
        int pos0 = row0 & 2047, b = row0 >> 11;
        int kc = pos0 >> 6, klo = pos0 & 63;
        f32x4 v = acc[i][j];
        f16x4 pk = {(f16)v[0], (f16)v[1], (f16)v[2], (f16)v[3]};
        int klosw = klo ^ ((dv & 7) << 3);  // pre-swizzle for attn LDS read
        *(f16x4*)&((f16*)out1)[((((size_t)b * NH + h) * 32 + kc) * 64 + dv) * 64 + klosw] = pk;
      }
    }
  }
}

// ---------- flash attention ----------
// 1-D grid 1024 blocks, chunked XCD remap: each XCD owns 16 bh, so a head's
// K/V (512 KB) is reused by its 8 q-blocks from one XCD L2.
// Per block: 256 threads (4 waves), each wave 32 q-rows x full D=64.
// Swapped QK^T: sacc = mfma(A=K, B=Q) -> lane holds P[q=l16][k=16nt+quad*4+r],
// which IS the B-fragment of mfma_f32_16x16x16f16 -> PV straight from registers.
// K/V double-buffered in LDS using the same proven 2-phase sync template.
// Kb/Vt arrive pre-XOR-swizzled (byte^((row&7)<<4)) so global_load_lds stays linear.
__global__ __launch_bounds__(256, 4) void attn(const f16* __restrict__ Qb,
                                               const f16* __restrict__ Kb,
                                               const f16* __restrict__ Vt,
                                               f16* __restrict__ attnb) {
  const int fid = blockIdx.x;
  const int lid = (fid & 7) * 128 + (fid >> 3);
  const int bh = lid >> 3, b = bh >> 4, h = bh & 15;
  const int q0 = (lid & 7) * 128;
  const int tid = threadIdx.x, lane = tid & 63, w = tid >> 6;
  const int quad = lane >> 4, l16 = lane & 15;
  const int sw = (l16 & 7) << 3;
  __shared__ __align__(16) f16 Ks[2][64 * 64];
  __shared__ __align__(16) f16 Vts[2][64 * 64];
  // Q rows for this wave: q0 + 32*w + qs*16 + l16 (Qb is linear, read to regs)
  const f16* qptr = Qb + ((size_t)bh * LQ + q0 + 32 * w + l16) * 64;
  f16x8 qf[2][2];
#pragma unroll
  for (int qs = 0; qs < 2; ++qs) {
    qf[qs][0] = *(const f16x8*)&qptr[qs * 16 * 64 + quad * 8];
    qf[qs][1] = *(const f16x8*)&qptr[qs * 16 * 64 + 32 + quad * 8];
  }
  const f16x4 ones4 = {(f16)1.f, (f16)1.f, (f16)1.f, (f16)1.f};
  f32x4 o[2][4] = {};
  f32x4 lacc[2] = {};
  float m_run[2] = {-1e30f, -1e30f};
  const f16* kbase = Kb + (size_t)bh * LK * 64;
  const f16* vtb = Vt + (size_t)bh * 32 * 4096;
  const int sr = tid >> 3, sc = (tid & 7) * 8;

  auto STAGE = [&](int c) {
    f16* ks = Ks[c & 1];
    f16* vs = Vts[c & 1];
    gll16(kbase + (size_t)(c * 64 + sr) * 64 + sc, &ks[sr * 64 + sc]);
    gll16(kbase + (size_t)(c * 64 + sr + 32) * 64 + sc, &ks[(sr + 32) * 64 + sc]);
    gll16(vtb + (size_t)(c * 64 + sr) * 64 + sc, &vs[sr * 64 + sc]);
    gll16(vtb + (size_t)(c * 64 + sr + 32) * 64 + sc, &vs[(sr + 32) * 64 + sc]);
  };

  constexpr int NC = LK / 64;
  STAGE(0);
  asm volatile("s_waitcnt vmcnt(0)" ::: "memory");
  __builtin_amdgcn_s_barrier();
  __builtin_amdgcn_sched_barrier(0);

  for (int c = 0; c < NC; ++c) {
    if (c + 1 < NC) STAGE(c + 1);  // issue next chunk; hides under QK^T/softmax/PV
    const f16* Ksb = Ks[c & 1];
    const f16* Vsb = Vts[c & 1];
    // S^T = K Q^T : lane gets S[q=l16][k=nt*16+quad*4+r]
    f32x4 sacc[2][4] = {};
#pragma unroll
    for (int nt = 0; nt < 4; ++nt) {
      const f16* krow = &Ksb[(nt * 16 + l16) * 64];
      f16x8 kf0 = *(const f16x8*)&krow[(quad * 8) ^ sw];
      f16x8 kf1 = *(const f16x8*)&krow[(32 + quad * 8) ^ sw];
#pragma unroll
      for (int qs = 0; qs < 2; ++qs) {
        sacc[qs][nt] = __builtin_amdgcn_mfma_f32_16x16x32_f16(kf0, qf[qs][0], sacc[qs][nt], 0, 0, 0);
        sacc[qs][nt] = __builtin_amdgcn_mfma_f32_16x16x32_f16(kf1, qf[qs][1], sacc[qs][nt], 0, 0, 0);
      }
    }
    // in-register online softmax (per-lane row max; cross-half reduce only)
    f16x4 pb[2][4];
#pragma unroll
    for (int qs = 0; qs < 2; ++qs) {
      float mx = sacc[qs][0][0];
#pragma unroll
      for (int nt = 0; nt < 4; ++nt)
#pragma unroll
        for (int r = 0; r < 4; ++r) mx = fmaxf(mx, sacc[qs][nt][r]);
      mx = fmaxf(mx, __shfl_xor(mx, 16, 64));
      mx = fmaxf(mx, __shfl_xor(mx, 32, 64));
      // defer-max: only rescale when max grew by > 8 (P bounded by e^8, f16-safe)
      if (!__all(mx <= m_run[qs] + 8.0f)) {
        float mn = fmaxf(m_run[qs], mx);
        float al = __expf(m_run[qs] - mn);
        m_run[qs] = mn;
#pragma unroll
        for (int r = 0; r < 4; ++r) lacc[qs][r] *= al;
#pragma unroll
        for (int dt = 0; dt < 4; ++dt)
#pragma unroll
          for (int r = 0; r < 4; ++r) o[qs][dt][r] *= al;
      }
      float m = m_run[qs];
#pragma unroll
      for (int nt = 0; nt < 4; ++nt) {
        f16x4 p;
#pragma unroll
        for (int r = 0; r < 4; ++r) p[r] = (f16)__expf(sacc[qs][nt][r] - m);
        pb[qs][nt] = p;
        // row-sum of P on the MFMA pipe: D[i][q] += sum_k 1 * P^T[k][q]
        lacc[qs] = __builtin_amdgcn_mfma_f32_16x16x16f16(ones4, p, lacc[qs], 0, 0, 0);
      }
    }
    // O^T += V^T P^T  (A = V^T fragment from LDS, B = P^T straight from registers)
#pragma unroll
    for (int dt = 0; dt < 4; ++dt)
#pragma unroll
      for (int nt = 0; nt < 4; ++nt) {
        f16x4 vf = *(const f16x4*)&Vsb[(dt * 16 + l16) * 64 + ((nt * 16 + quad * 4) ^ sw)];
#pragma unroll
        for (int qs = 0; qs < 2; ++qs)
          o[qs][dt] = __builtin_amdgcn_mfma_f32_16x16x16f16(vf, pb[qs][nt], o[qs][dt], 0, 0, 0);
      }
    // next chunk landed (own loads) + all waves done reading current buffers
    asm volatile("s_waitcnt vmcnt(0)" ::: "memory");
    __builtin_amdgcn_s_barrier();
    __builtin_amdgcn_sched_barrier(0);
  }
  // epilogue: o holds O^T (lane: dv = dt*16+quad*4+r, q = l16) -> f16x4 stores
#pragma unroll
  for (int qs = 0; qs < 2; ++qs) {
    float inv = 1.0f / lacc[qs][0];
    int q = q0 + 32 * w + qs * 16 + l16;
#pragma unroll
    for (int dt = 0; dt < 4; ++dt) {
      f16x4 ov;
#pragma unroll
      for (int r = 0; r < 4; ++r) ov[r] = (f16)(o[qs][dt][r] * inv);
      *(f16x4*)&attnb[((size_t)b * LQ + q) * HID + h * 64 + dt * 16 + quad * 4] = ov;
    }
  }
}

extern "C" void kernel_launch(void* const* d_in, const int* in_sizes, int n_in,
                              void* d_out, int out_size, void* d_ws, size_t ws_size,
                              hipStream_t stream) {
  const float* x = (const float*)d_in[0];
  const float* y = (const float*)d_in[1];
  const float* Wq = (const float*)d_in[2];
  const float* Wkv = (const float*)d_in[3];
  const float* Wo = (const float*)d_in[4];
  float* out = (float*)d_out;

  char* p = (char*)d_ws;
  f16* xb = (f16*)p;    p += (size_t)B_ * LQ * HID * 2;      // 16 MB
  f16* yb = (f16*)p;    p += (size_t)B_ * LK * HID * 2;      // 32 MB
  f16* Wqb = (f16*)p;   p += (size_t)HID * HID * 2;          // 2 MB
  f16* Wkvb = (f16*)p;  p += (size_t)2 * HID * HID * 2;      // 4 MB
  f16* Wob = (f16*)p;   p += (size_t)HID * HID * 2;          // 2 MB
  f16* Qb = (f16*)p;    p += (size_t)B_ * LQ * HID * 2;      // 16 MB
  f16* Kb = (f16*)p;    p += (size_t)B_ * LK * HID * 2;      // 32 MB
  f16* Vt = (f16*)p;    p += (size_t)B_ * LK * HID * 2;      // 32 MB
  f16* attnb = xb;  // xb dead after GEMM1

  auto cvt = [&](const float* s, f16* d, size_t n) {
    cvt_f32_f16<<<dim3((unsigned)((n / 4 + 255) / 256)), 256, 0, stream>>>(s, d, (int)(n / 4));
  };
  cvt(x, xb, (size_t)B_ * LQ * HID);
  cvt(y, yb, (size_t)B_ * LK * HID);
  cvt(Wq, Wqb, (size_t)HID * HID);
  cvt(Wkv, Wkvb, (size_t)2 * HID * HID);
  cvt(Wo, Wob, (size_t)HID * HID);

  // Q = RoPE(x @ Wq^T) -> Qb [bh][lq][64]
  gemm_fused<0><<<dim3(HID / 128, B_ * LQ / 128), 256, 0, stream>>>(
      xb, Wqb, Qb, nullptr, B_ * LQ, HID, HID);
  // KV = y @ Wkv^T -> Kb (RoPE, swizzled) + Vt (transposed, chunk-tiled, swizzled)
  gemm_fused<1><<<dim3(2 * HID / 128, B_ * LK / 128), 256, 0, stream>>>(
      yb, Wkvb, Kb, Vt, B_ * LK, 2 * HID, HID);

  // attention -> attnb [B*LQ, 1024] fp16; 1-D grid + chunked remap pins KV per XCD
  attn<<<dim3(B_ * NH * (LQ / 128)), 256, 0, stream>>>(Qb, Kb, Vt, attnb);

  // out = attn @ Wo^T -> fp32
  gemm_fused<2><<<dim3(HID / 128, B_ * LQ / 128), 256, 0, stream>>>(
      attnb, Wob, out, nullptr, B_ * LQ, HID, HID);
}

// Round 5
// 382.723 us; speedup vs baseline: 1.3407x; 1.0820x over previous
//
#include <hip/hip_runtime.h>

typedef _Float16 f16;
typedef __attribute__((ext_vector_type(8))) _Float16 f16x8;
typedef __attribute__((ext_vector_type(4))) _Float16 f16x4;
typedef __attribute__((ext_vector_type(4))) float f32x4;

constexpr int B_ = 8, LQ = 1024, LK = 2048, NH = 16, HID = 1024;

// async global->LDS, 16B per lane; LDS dest must be wave-uniform base + lane*16
__device__ __forceinline__ void gll16(const void* g, void* l) {
  __builtin_amdgcn_global_load_lds((const __attribute__((address_space(1))) void*)g,
                                   (__attribute__((address_space(3))) void*)l, 16, 0, 0);
}

// ---------- fp32 -> fp16 cast (vectorized) ----------
__global__ __launch_bounds__(256) void cvt_f32_f16(const float* __restrict__ src,
                                                   f16* __restrict__ dst, int n4) {
  int t = blockIdx.x * 256 + threadIdx.x;
  if (t >= n4) return;
  float4 v = ((const float4*)src)[t];
  f16x4 o = {(f16)v.x, (f16)v.y, (f16)v.z, (f16)v.w};
  ((f16x4*)dst)[t] = o;
}

// ---------- fused NT GEMM: C[M,N] = A[M,K] * B[N,K]^T ----------
// Proven 2-phase pipeline (R3): STAGE(t+1) first, compute tile t while loads fly,
// ONE vmcnt(0)+s_barrier per tile, sched_barrier(0) pinning motion across barriers.
// R4 (untested due to infra failure; resubmitted verbatim): T2 XOR swizzle on LDS
// tiles via rule #21 -- DMA dest stays LINEAR, global source 16B-chunk is permuted
// (LDS[r][c] = G[r][c^(r&7)]), fragment reads XOR the same pattern. Kills the
// 16-way conflict of 128B rows (35% of R3 cycles).
// T5 setprio around MFMA cluster, T1 bijective XCD-chunked block remap.
// MODE 0: Q proj -> RoPE -> Qb [bh][lq][64]           (out0=Qb, linear rows)
// MODE 1: KV proj -> wn=0: RoPE K -> Kb [bh][lk][64]  (row-XOR-swizzled for attn LDS)
//                    wn=1: V^T -> Vt [bh][kc][dv][64] (row-XOR-swizzled for attn LDS)
// MODE 2: plain fp32 output (out0)
template <int MODE>
__global__ __launch_bounds__(256) void gemm_fused(const f16* __restrict__ A,
                                                  const f16* __restrict__ Bm,
                                                  void* __restrict__ out0,
                                                  void* __restrict__ out1,
                                                  int M, int N, int K) {
  // T1: chunked XCD remap (requires nwg % 8 == 0 -- true for all launches here)
  const int gx = gridDim.x;
  const int nwg = gx * gridDim.y;
  const int cpx = nwg >> 3;
  const int fid = blockIdx.y * gx + blockIdx.x;
  const int lid = (fid & 7) * cpx + (fid >> 3);
  const int n0 = (lid % gx) * 128, m0 = (lid / gx) * 128;
  const int tid = threadIdx.x, lane = tid & 63, w = tid >> 6;
  const int wm = w >> 1, wn = w & 1;
  const int quad = lane >> 4, l16 = lane & 15;
  __shared__ __align__(16) f16 As[2][128 * 64];
  __shared__ __align__(16) f16 Bs[2][128 * 64];
  f32x4 acc[4][4] = {};
  const int sr = tid >> 3, sc8 = tid & 7;
  const int ldst = sr * 64 + sc8 * 8;  // linear LDS dest (wave base + lane*16B)
  // pre-swizzled global source: LDS chunk sc8 of row r holds global chunk sc8^(r&7)
  const f16* ga = A + (size_t)(m0 + sr) * K + ((sc8 ^ (sr & 7)) << 3);
  const f16* gb = Bm + (size_t)(n0 + sr) * K + ((sc8 ^ (sr & 7)) << 3);
  const int NT = K >> 6;

  auto STAGE = [&](int t) {
    f16* as = As[t & 1];
    f16* bs = Bs[t & 1];
    const int k0 = t << 6;
#pragma unroll
    for (int p = 0; p < 4; ++p) {
      gll16(ga + (size_t)p * 32 * K + k0, &as[ldst + p * 32 * 64]);
      gll16(gb + (size_t)p * 32 * K + k0, &bs[ldst + p * 32 * 64]);
    }
  };

  // prologue: stage tile 0, full drain, join
  STAGE(0);
  asm volatile("s_waitcnt vmcnt(0)" ::: "memory");
  __builtin_amdgcn_s_barrier();
  __builtin_amdgcn_sched_barrier(0);

  const int swr = l16 & 7;
  for (int t = 0; t < NT; ++t) {
    if (t + 1 < NT) STAGE(t + 1);  // issue next tile; latency hides under MFMAs below
    const f16* as = As[t & 1];
    const f16* bs = Bs[t & 1];
#pragma unroll
    for (int ks = 0; ks < 2; ++ks) {
      f16x8 af[4], bfr[4];
#pragma unroll
      for (int i = 0; i < 4; ++i) {
        const int csw = ((ks * 4 + quad) ^ swr) << 3;  // swizzled chunk read
        af[i] = *(const f16x8*)&as[(wm * 64 + i * 16 + l16) * 64 + csw];
        bfr[i] = *(const f16x8*)&bs[(wn * 64 + i * 16 + l16) * 64 + csw];
      }
      __builtin_amdgcn_s_setprio(1);
#pragma unroll
      for (int i = 0; i < 4; ++i)
#pragma unroll
        for (int j = 0; j < 4; ++j)
          acc[i][j] = __builtin_amdgcn_mfma_f32_16x16x32_f16(af[i], bfr[j], acc[i][j], 0, 0, 0);
      __builtin_amdgcn_s_setprio(0);
    }
    // next tile fully landed (own loads) + all waves done reading current buf
    asm volatile("s_waitcnt vmcnt(0)" ::: "memory");
    __builtin_amdgcn_s_barrier();
    __builtin_amdgcn_sched_barrier(0);
  }
  if (MODE == 2) {
#pragma unroll
    for (int i = 0; i < 4; ++i)
#pragma unroll
      for (int j = 0; j < 4; ++j) {
        int row = m0 + wm * 64 + i * 16 + quad * 4;
        int col = n0 + wn * 64 + j * 16 + l16;
#pragma unroll
        for (int r = 0; r < 4; ++r)
          ((float*)out0)[(size_t)(row + r) * N + col] = acc[i][j][r];
      }
    return;
  }
  constexpr int LSH = (MODE == 0) ? 10 : 11;
  constexpr int LMSK = (MODE == 0) ? 1023 : 2047;
  const int Ltok = LMSK + 1;
  if (MODE == 0 || wn == 0) {
    // RoPE path. col c: head h = c / headspan, d = (c per-head K-dim index)
#pragma unroll
    for (int j = 0; j < 4; ++j) {
      int c = n0 + wn * 64 + j * 16 + l16;
      int h = (MODE == 0) ? (c >> 6) : (n0 >> 7);
      int d = (MODE == 0) ? (c & 63) : (j * 16 + l16);
      float inv_t = exp2f((float)(d >> 1) * -0.41524101186091903f);
#pragma unroll
      for (int i = 0; i < 4; ++i) {
        f32x4 v = acc[i][j];
        f32x4 pv;
#pragma unroll
        for (int r = 0; r < 4; ++r) pv[r] = __shfl_xor(v[r], 1, 64);
        int row0 = m0 + wm * 64 + i * 16 + quad * 4;
#pragma unroll
        for (int r = 0; r < 4; ++r) {
          int row = row0 + r;
          int pos = row & LMSK, b = row >> LSH;
          float ang = (float)pos * inv_t;
          float sn, cs;
          __sincosf(ang, &sn, &cs);
          float o = (d & 1) ? (v[r] * cs + pv[r] * sn) : (v[r] * cs - pv[r] * sn);
          // K rows get the attn-LDS XOR swizzle pre-applied (16B chunks within 128B row)
          int dsw = (MODE == 1) ? (d ^ ((pos & 7) << 3)) : d;
          ((f16*)out0)[(((size_t)b * NH + h) * Ltok + pos) * 64 + dsw] = (f16)o;
        }
      }
    }
  } else {
    // V path (MODE 1, wn==1): V^T tiled: Vt[((bh*32 + kc)*64 + dv)*64 + klo], row=dv swizzled
    const int h = n0 >> 7;
#pragma unroll
    for (int j = 0; j < 4; ++j) {
      int dv = j * 16 + l16;
#pragma unroll
      for (int i = 0; i < 4; ++i) {
        int row0 = m0 + wm * 64 + i * 16 + quad * 4;
        int pos0 = row0 & 2047, b = row0 >> 11;
        int kc = pos0 >> 6, klo = pos0 & 63;
        f32x4 v = acc[i][j];
        f16x4 pk = {(f16)v[0], (f16)v[1], (f16)v[2], (f16)v[3]};
        int klosw = klo ^ ((dv & 7) << 3);  // pre-swizzle for attn LDS read
        *(f16x4*)&((f16*)out1)[((((size_t)b * NH + h) * 32 + kc) * 64 + dv) * 64 + klosw] = pk;
      }
    }
  }
}

// ---------- flash attention ----------
// 1-D grid 1024 blocks, chunked XCD remap: each XCD owns 16 bh, so a head's
// K/V (512 KB) is reused by its 8 q-blocks from one XCD L2.
// Per block: 256 threads (4 waves), each wave 32 q-rows x full D=64.
// Swapped QK^T: sacc = mfma(A=K, B=Q) -> lane holds P[q=l16][k=16nt+quad*4+r],
// which IS the B-fragment of mfma_f32_16x16x16f16 -> PV straight from registers.
// K/V double-buffered in LDS using the same proven 2-phase sync template.
// Kb/Vt arrive pre-XOR-swizzled (byte^((row&7)<<4)) so global_load_lds stays linear.
__global__ __launch_bounds__(256, 4) void attn(const f16* __restrict__ Qb,
                                               const f16* __restrict__ Kb,
                                               const f16* __restrict__ Vt,
                                               f16* __restrict__ attnb) {
  const int fid = blockIdx.x;
  const int lid = (fid & 7) * 128 + (fid >> 3);
  const int bh = lid >> 3, b = bh >> 4, h = bh & 15;
  const int q0 = (lid & 7) * 128;
  const int tid = threadIdx.x, lane = tid & 63, w = tid >> 6;
  const int quad = lane >> 4, l16 = lane & 15;
  const int sw = (l16 & 7) << 3;
  __shared__ __align__(16) f16 Ks[2][64 * 64];
  __shared__ __align__(16) f16 Vts[2][64 * 64];
  // Q rows for this wave: q0 + 32*w + qs*16 + l16 (Qb is linear, read to regs)
  const f16* qptr = Qb + ((size_t)bh * LQ + q0 + 32 * w + l16) * 64;
  f16x8 qf[2][2];
#pragma unroll
  for (int qs = 0; qs < 2; ++qs) {
    qf[qs][0] = *(const f16x8*)&qptr[qs * 16 * 64 + quad * 8];
    qf[qs][1] = *(const f16x8*)&qptr[qs * 16 * 64 + 32 + quad * 8];
  }
  const f16x4 ones4 = {(f16)1.f, (f16)1.f, (f16)1.f, (f16)1.f};
  f32x4 o[2][4] = {};
  f32x4 lacc[2] = {};
  float m_run[2] = {-1e30f, -1e30f};
  const f16* kbase = Kb + (size_t)bh * LK * 64;
  const f16* vtb = Vt + (size_t)bh * 32 * 4096;
  const int sr = tid >> 3, sc = (tid & 7) * 8;

  auto STAGE = [&](int c) {
    f16* ks = Ks[c & 1];
    f16* vs = Vts[c & 1];
    gll16(kbase + (size_t)(c * 64 + sr) * 64 + sc, &ks[sr * 64 + sc]);
    gll16(kbase + (size_t)(c * 64 + sr + 32) * 64 + sc, &ks[(sr + 32) * 64 + sc]);
    gll16(vtb + (size_t)(c * 64 + sr) * 64 + sc, &vs[sr * 64 + sc]);
    gll16(vtb + (size_t)(c * 64 + sr + 32) * 64 + sc, &vs[(sr + 32) * 64 + sc]);
  };

  constexpr int NC = LK / 64;
  STAGE(0);
  asm volatile("s_waitcnt vmcnt(0)" ::: "memory");
  __builtin_amdgcn_s_barrier();
  __builtin_amdgcn_sched_barrier(0);

  for (int c = 0; c < NC; ++c) {
    if (c + 1 < NC) STAGE(c + 1);  // issue next chunk; hides under QK^T/softmax/PV
    const f16* Ksb = Ks[c & 1];
    const f16* Vsb = Vts[c & 1];
    // S^T = K Q^T : lane gets S[q=l16][k=nt*16+quad*4+r]
    f32x4 sacc[2][4] = {};
#pragma unroll
    for (int nt = 0; nt < 4; ++nt) {
      const f16* krow = &Ksb[(nt * 16 + l16) * 64];
      f16x8 kf0 = *(const f16x8*)&krow[(quad * 8) ^ sw];
      f16x8 kf1 = *(const f16x8*)&krow[(32 + quad * 8) ^ sw];
#pragma unroll
      for (int qs = 0; qs < 2; ++qs) {
        sacc[qs][nt] = __builtin_amdgcn_mfma_f32_16x16x32_f16(kf0, qf[qs][0], sacc[qs][nt], 0, 0, 0);
        sacc[qs][nt] = __builtin_amdgcn_mfma_f32_16x16x32_f16(kf1, qf[qs][1], sacc[qs][nt], 0, 0, 0);
      }
    }
    // in-register online softmax (per-lane row max; cross-half reduce only)
    f16x4 pb[2][4];
#pragma unroll
    for (int qs = 0; qs < 2; ++qs) {
      float mx = sacc[qs][0][0];
#pragma unroll
      for (int nt = 0; nt < 4; ++nt)
#pragma unroll
        for (int r = 0; r < 4; ++r) mx = fmaxf(mx, sacc[qs][nt][r]);
      mx = fmaxf(mx, __shfl_xor(mx, 16, 64));
      mx = fmaxf(mx, __shfl_xor(mx, 32, 64));
      // defer-max: only rescale when max grew by > 8 (P bounded by e^8, f16-safe)
      if (!__all(mx <= m_run[qs] + 8.0f)) {
        float mn = fmaxf(m_run[qs], mx);
        float al = __expf(m_run[qs] - mn);
        m_run[qs] = mn;
#pragma unroll
        for (int r = 0; r < 4; ++r) lacc[qs][r] *= al;
#pragma unroll
        for (int dt = 0; dt < 4; ++dt)
#pragma unroll
          for (int r = 0; r < 4; ++r) o[qs][dt][r] *= al;
      }
      float m = m_run[qs];
#pragma unroll
      for (int nt = 0; nt < 4; ++nt) {
        f16x4 p;
#pragma unroll
        for (int r = 0; r < 4; ++r) p[r] = (f16)__expf(sacc[qs][nt][r] - m);
        pb[qs][nt] = p;
        // row-sum of P on the MFMA pipe: D[i][q] += sum_k 1 * P^T[k][q]
        lacc[qs] = __builtin_amdgcn_mfma_f32_16x16x16f16(ones4, p, lacc[qs], 0, 0, 0);
      }
    }
    // O^T += V^T P^T  (A = V^T fragment from LDS, B = P^T straight from registers)
#pragma unroll
    for (int dt = 0; dt < 4; ++dt)
#pragma unroll
      for (int nt = 0; nt < 4; ++nt) {
        f16x4 vf = *(const f16x4*)&Vsb[(dt * 16 + l16) * 64 + ((nt * 16 + quad * 4) ^ sw)];
#pragma unroll
        for (int qs = 0; qs < 2; ++qs)
          o[qs][dt] = __builtin_amdgcn_mfma_f32_16x16x16f16(vf, pb[qs][nt], o[qs][dt], 0, 0, 0);
      }
    // next chunk landed (own loads) + all waves done reading current buffers
    asm volatile("s_waitcnt vmcnt(0)" ::: "memory");
    __builtin_amdgcn_s_barrier();
    __builtin_amdgcn_sched_barrier(0);
  }
  // epilogue: o holds O^T (lane: dv = dt*16+quad*4+r, q = l16) -> f16x4 stores
#pragma unroll
  for (int qs = 0; qs < 2; ++qs) {
    float inv = 1.0f / lacc[qs][0];
    int q = q0 + 32 * w + qs * 16 + l16;
#pragma unroll
    for (int dt = 0; dt < 4; ++dt) {
      f16x4 ov;
#pragma unroll
      for (int r = 0; r < 4; ++r) ov[r] = (f16)(o[qs][dt][r] * inv);
      *(f16x4*)&attnb[((size_t)b * LQ + q) * HID + h * 64 + dt * 16 + quad * 4] = ov;
    }
  }
}

extern "C" void kernel_launch(void* const* d_in, const int* in_sizes, int n_in,
                              void* d_out, int out_size, void* d_ws, size_t ws_size,
                              hipStream_t stream) {
  const float* x = (const float*)d_in[0];
  const float* y = (const float*)d_in[1];
  const float* Wq = (const float*)d_in[2];
  const float* Wkv = (const float*)d_in[3];
  const float* Wo = (const float*)d_in[4];
  float* out = (float*)d_out;

  char* p = (char*)d_ws;
  f16* xb = (f16*)p;    p += (size_t)B_ * LQ * HID * 2;      // 16 MB
  f16* yb = (f16*)p;    p += (size_t)B_ * LK * HID * 2;      // 32 MB
  f16* Wqb = (f16*)p;   p += (size_t)HID * HID * 2;          // 2 MB
  f16* Wkvb = (f16*)p;  p += (size_t)2 * HID * HID * 2;      // 4 MB
  f16* Wob = (f16*)p;   p += (size_t)HID * HID * 2;          // 2 MB
  f16* Qb = (f16*)p;    p += (size_t)B_ * LQ * HID * 2;      // 16 MB
  f16* Kb = (f16*)p;    p += (size_t)B_ * LK * HID * 2;      // 32 MB
  f16* Vt = (f16*)p;    p += (size_t)B_ * LK * HID * 2;      // 32 MB
  f16* attnb = xb;  // xb dead after GEMM1

  auto cvt = [&](const float* s, f16* d, size_t n) {
    cvt_f32_f16<<<dim3((unsigned)((n / 4 + 255) / 256)), 256, 0, stream>>>(s, d, (int)(n / 4));
  };
  cvt(x, xb, (size_t)B_ * LQ * HID);
  cvt(y, yb, (size_t)B_ * LK * HID);
  cvt(Wq, Wqb, (size_t)HID * HID);
  cvt(Wkv, Wkvb, (size_t)2 * HID * HID);
  cvt(Wo, Wob, (size_t)HID * HID);

  // Q = RoPE(x @ Wq^T) -> Qb [bh][lq][64]
  gemm_fused<0><<<dim3(HID / 128, B_ * LQ / 128), 256, 0, stream>>>(
      xb, Wqb, Qb, nullptr, B_ * LQ, HID, HID);
  // KV = y @ Wkv^T -> Kb (RoPE, swizzled) + Vt (transposed, chunk-tiled, swizzled)
  gemm_fused<1><<<dim3(2 * HID / 128, B_ * LK / 128), 256, 0, stream>>>(
      yb, Wkvb, Kb, Vt, B_ * LK, 2 * HID, HID);

  // attention -> attnb [B*LQ, 1024] fp16; 1-D grid + chunked remap pins KV per XCD
  attn<<<dim3(B_ * NH * (LQ / 128)), 256, 0, stream>>>(Qb, Kb, Vt, attnb);

  // out = attn @ Wo^T -> fp32
  gemm_fused<2><<<dim3(HID / 128, B_ * LQ / 128), 256, 0, stream>>>(
      attnb, Wob, out, nullptr, B_ * LQ, HID, HID);
}